// Round 11
// baseline (243.870 us; speedup 1.0000x reference)
//
#include <hip/hip_runtime.h>
#include <hip/hip_bf16.h>
#include <cstdint>

#define LQ 1024
#define LK 1024
#define DD 512
#define NB 16
#define QB 64
#define KB 32
#define NT (LK / KB)
#define CSTRIDE 1088  // 1024 + 64: linear-in-s S^T reads with 8-quad bank spread
#define CSZ (32 * CSTRIDE)

typedef short bf16x8 __attribute__((ext_vector_type(8)));
typedef float f32x4 __attribute__((ext_vector_type(4)));

__device__ __forceinline__ uint16_t f2bf(float f) {
  uint32_t u = __builtin_bit_cast(uint32_t, f);
  u = (u + 0x7fffu + ((u >> 16) & 1u)) >> 16;  // RNE; inputs finite
  return (uint16_t)u;
}

__device__ __forceinline__ void load_lds16(const void* g, void* l) {
  __builtin_amdgcn_global_load_lds(
      (const __attribute__((address_space(1))) uint32_t*)g,
      (__attribute__((address_space(3))) uint32_t*)l, 16, 0, 0);
}

// ---------- fused prepass: C fp32 -> Cb bf16 [B][Lk][D] + Ct bf16 [B][D][Lk] ----------
__global__ __launch_bounds__(256) void prep_kernel(const float* __restrict__ c,
                                                   uint16_t* __restrict__ cb,
                                                   uint16_t* __restrict__ ct) {
  __shared__ float t[32][33];
  const int k0 = blockIdx.x * 32, d0 = blockIdx.y * 32, b = blockIdx.z;
  const float* src = c + (size_t)b * LK * DD;
  uint16_t* cbd = cb + (size_t)b * LK * DD;
  uint16_t* ctd = ct + (size_t)b * DD * LK;
  const int tx = threadIdx.x, ty = threadIdx.y;
  for (int j = 0; j < 4; ++j) {
    int k = ty + j * 8;
    float v = src[(size_t)(k0 + k) * DD + d0 + tx];
    t[k][tx] = v;
    cbd[(size_t)(k0 + k) * DD + d0 + tx] = f2bf(v);
  }
  __syncthreads();
  for (int j = 0; j < 4; ++j) {
    int d = ty + j * 8;
    ctd[(size_t)(d0 + d) * LK + k0 + tx] = f2bf(t[tx][d]);
  }
}

// ---------------- fused attention + residual + LayerNorm ----------------
// grid = 256 (B=16 x 16 q-blocks of 64 rows), block = 512 (8 waves).
// r9 body (best measured: 76.4 us attn) with SINGLE-buffered LDS tiles so
// LDS/block = ~72 KB -> 2 blocks/CU (4 waves/SIMD). Traffic unchanged vs r9.
// Within-block the staging DMA latency is exposed (3 barriers/iter); the
// co-resident block fills those stalls (m97-style implicit overlap).
__global__ __launch_bounds__(512, 4) void attn_kernel(
    const uint16_t* __restrict__ Cb, const uint16_t* __restrict__ Ctb,
    const float* __restrict__ Qf, const float* __restrict__ gamma,
    const float* __restrict__ beta, float* __restrict__ out) {
  __shared__ uint4 cs4[CSZ / 16];         // 34 KB C tile [32 kk][512 d] bf16
  __shared__ uint4 cts4[32 * 1024 / 16];  // 32 KB Ct tile [512 d][32 kk] bf16
  __shared__ char plds[64 * 80];          // 5 KB P [64 q][32 kk], stride 80
  __shared__ float denom_s[QB];
  __shared__ float rsum_s[QB], rsumsq_s[QB], mean_s[QB], rstd_s[QB];

  const int tid = threadIdx.x;
  const int w = tid >> 6, l = tid & 63, c = l & 15, g = l >> 4;
  const int orig = blockIdx.x;
  const int virt = ((orig & 7) << 5) | (orig >> 3);  // 256 % 8 == 0: bijective
  const int b = virt >> 4, qblk = virt & 15;
  const int q0 = qblk * QB;
  const int mt = w & 1, qt = w >> 1;
  const float scale = 0.044194173824159216f;  // 1/sqrt(512)

  if (tid < QB) { denom_s[tid] = 0.f; rsum_s[tid] = 0.f; rsumsq_s[tid] = 0.f; }

  // Q fragments (B operand of S^T) from fp32, converted in-register
  bf16x8 qfrag[16];
  {
    const float* qrow = Qf + ((size_t)b * LQ + q0 + qt * 16 + c) * DD;
    for (int s = 0; s < 16; ++s) {
      float4 a0 = *(const float4*)(qrow + s * 32 + g * 8);
      float4 a1 = *(const float4*)(qrow + s * 32 + g * 8 + 4);
      ushort4 u0, u1;
      u0.x = f2bf(a0.x); u0.y = f2bf(a0.y); u0.z = f2bf(a0.z); u0.w = f2bf(a0.w);
      u1.x = f2bf(a1.x); u1.y = f2bf(a1.y); u1.z = f2bf(a1.z); u1.w = f2bf(a1.w);
      union { ushort4 u[2]; bf16x8 v; } pk;
      pk.u[0] = u0; pk.u[1] = u1;
      qfrag[s] = pk.v;
    }
  }

  const int kkA = mt * 16 + c;
  const int aoff = kkA * CSTRIDE + ((g ^ (kkA & 3)) * 16);

  f32x4 oacc[4][4];
  for (int i = 0; i < 4; ++i)
    for (int j = 0; j < 4; ++j) oacc[i][j] = (f32x4){0.f, 0.f, 0.f, 0.f};
  float dacc = 0.f;

  const char* cbyte = (const char*)Cb + (size_t)b * LK * DD * 2;
  const char* ctbyte = (const char*)Ctb + (size_t)b * DD * LK * 2;

  int csrcoff[4];
  for (int j = 0; j < 4; ++j) {
    int r = w * 4 + j;
    csrcoff[j] = r * 1024 + ((l * 16) ^ ((r & 3) << 4));
  }

  char* cs = (char*)cs4;
  char* cts = (char*)cts4;
  const int pwoff = (qt * 16 + c) * 80 + (mt * 16 + g * 4) * 2;
  const int proff = c * 80 + g * 16;

  auto stageC = [&](int kt2) {
    const char* s0 = cbyte + (size_t)kt2 * 32768;
    for (int j = 0; j < 4; ++j)
      load_lds16(s0 + csrcoff[j], cs + (w * 4 + j) * CSTRIDE);
  };
  auto stageCT = [&](int kt2) {
    const int kk0 = kt2 * KB;
    for (int j = 0; j < 4; ++j) {
      int d0l = w * 64 + j * 16;
      int d = d0l + (l >> 2);
      const char* src =
          ctbyte + (size_t)d * 2048 + kk0 * 2 + (((l & 3) * 16) ^ ((d & 3) << 4));
      load_lds16(src, cts + d0l * 64);
    }
  };

  stageC(0);
  stageCT(0);
  __syncthreads();  // prologue drain; zero-inits visible

  for (int kt = 0; kt < NT; ++kt) {
    // S^T(kt): lane (c,g) -> kk=mt*16+g*4+i, q=qt*16+c; 4 independent chains
    f32x4 s0v = {0.f, 0.f, 0.f, 0.f}, s1v = {0.f, 0.f, 0.f, 0.f};
    f32x4 s2v = {0.f, 0.f, 0.f, 0.f}, s3v = {0.f, 0.f, 0.f, 0.f};
    {
      const char* ar = cs + aoff;
      for (int s = 0; s < 4; ++s) {
        bf16x8 a0 = *(const bf16x8*)(ar + s * 64);
        bf16x8 a1 = *(const bf16x8*)(ar + (s + 4) * 64);
        bf16x8 a2 = *(const bf16x8*)(ar + (s + 8) * 64);
        bf16x8 a3 = *(const bf16x8*)(ar + (s + 12) * 64);
        s0v = __builtin_amdgcn_mfma_f32_16x16x32_bf16(a0, qfrag[s], s0v, 0, 0, 0);
        s1v = __builtin_amdgcn_mfma_f32_16x16x32_bf16(a1, qfrag[s + 4], s1v, 0, 0, 0);
        s2v = __builtin_amdgcn_mfma_f32_16x16x32_bf16(a2, qfrag[s + 8], s2v, 0, 0, 0);
        s3v = __builtin_amdgcn_mfma_f32_16x16x32_bf16(a3, qfrag[s + 12], s3v, 0, 0, 0);
      }
    }
    // P(kt) = exp(tanh(s*scale)) in [e^-1, e^1] -> no max tracking
    {
      float pv[4];
      for (int i = 0; i < 4; ++i) {
        float sv = ((s0v[i] + s1v[i]) + (s2v[i] + s3v[i])) * scale;
        float e2 = __expf(sv * 2.f);
        float r = __builtin_amdgcn_rcpf(e2 + 1.f);
        float th = (e2 - 1.f) * r;
        float p = __expf(th);
        pv[i] = p;
        dacc += p;
      }
      uint2 pk;
      asm("v_cvt_pk_bf16_f32 %0, %1, %2" : "=v"(pk.x) : "v"(pv[0]), "v"(pv[1]));
      asm("v_cvt_pk_bf16_f32 %0, %1, %2" : "=v"(pk.y) : "v"(pv[2]), "v"(pv[3]));
      *(uint2*)(plds + pwoff) = pk;
    }
    // bar1: all cs reads + P write done (DS only) -> cs is free to restage
    asm volatile("s_waitcnt lgkmcnt(0)" ::: "memory");
    __builtin_amdgcn_s_barrier();
    __builtin_amdgcn_sched_barrier(0);
    if (kt + 1 < NT) stageC(kt + 1);  // DMA into cs, overlaps PV below

    // PV(kt): O[q][d] += P[q][kk] * C[kk][d]; wave w owns d in [w*64, w*64+64)
    {
      bf16x8 pa[4], pb[4];
      for (int q2 = 0; q2 < 4; ++q2)
        pa[q2] = *(const bf16x8*)(plds + proff + q2 * 1280);
      for (int nt = 0; nt < 4; ++nt) {
        int d = w * 64 + nt * 16 + c;
        pb[nt] = *(const bf16x8*)(cts + d * 64 + ((g * 16) ^ ((d & 3) << 4)));
      }
      for (int q2 = 0; q2 < 4; ++q2)
        for (int n2 = 0; n2 < 4; ++n2)
          oacc[q2][n2] =
              __builtin_amdgcn_mfma_f32_16x16x32_bf16(pa[q2], pb[n2], oacc[q2][n2], 0, 0, 0);
    }
    // bar2: all cts + plds reads done -> cts free to restage
    asm volatile("s_waitcnt lgkmcnt(0)" ::: "memory");
    __builtin_amdgcn_s_barrier();
    __builtin_amdgcn_sched_barrier(0);
    if (kt + 1 < NT) stageCT(kt + 1);  // DMA into cts
    // bar3: full drain -- both DMAs landed before next iter's reads
    __syncthreads();
  }

  // denom: reduce over g (shfl 16,32), combine mt-halves via LDS atomics
  float dv = dacc;
  dv += __shfl_xor(dv, 16);
  dv += __shfl_xor(dv, 32);
  if (l < 16) atomicAdd(&denom_s[qt * 16 + l], dv);
  __syncthreads();

  // epilogue: y = O/denom + query (fp32), then LayerNorm over D
  const float* qsrc = Qf + ((size_t)b * LQ + q0) * DD;
  for (int q2 = 0; q2 < 4; ++q2)
    for (int i = 0; i < 4; ++i) {
      int row = q2 * 16 + g * 4 + i;
      float inv = 1.f / denom_s[row];
      for (int nt = 0; nt < 4; ++nt) {
        int d = w * 64 + nt * 16 + c;
        float o = oacc[q2][nt][i] * inv + qsrc[(size_t)row * DD + d];
        oacc[q2][nt][i] = o;
      }
    }
  for (int q2 = 0; q2 < 4; ++q2)
    for (int i = 0; i < 4; ++i) {
      float s1 = 0.f, s2 = 0.f;
      for (int nt = 0; nt < 4; ++nt) {
        float v = oacc[q2][nt][i];
        s1 += v;
        s2 += v * v;
      }
      s1 += __shfl_xor(s1, 1); s2 += __shfl_xor(s2, 1);
      s1 += __shfl_xor(s1, 2); s2 += __shfl_xor(s2, 2);
      s1 += __shfl_xor(s1, 4); s2 += __shfl_xor(s2, 4);
      s1 += __shfl_xor(s1, 8); s2 += __shfl_xor(s2, 8);
      if (c == 0) {
        int row = q2 * 16 + g * 4 + i;
        atomicAdd(&rsum_s[row], s1);
        atomicAdd(&rsumsq_s[row], s2);
      }
    }
  __syncthreads();
  if (tid < QB) {
    float m = rsum_s[tid] * (1.f / DD);
    float var = rsumsq_s[tid] * (1.f / DD) - m * m;
    mean_s[tid] = m;
    rstd_s[tid] = rsqrtf(fmaxf(var, 0.f) + 1e-6f);
  }
  __syncthreads();
  float* op = out + ((size_t)b * LQ + q0) * DD;
  for (int q2 = 0; q2 < 4; ++q2)
    for (int i = 0; i < 4; ++i) {
      int row = q2 * 16 + g * 4 + i;
      float m = mean_s[row], r = rstd_s[row];
      for (int nt = 0; nt < 4; ++nt) {
        int d = w * 64 + nt * 16 + c;
        op[(size_t)row * DD + d] = gamma[d] * ((oacc[q2][nt][i] - m) * r) + beta[d];
      }
    }
}

// ---------------- slow-but-correct fallback (if ws too small) ----------------
__global__ __launch_bounds__(256) void naive_kernel(const float* __restrict__ Q,
                                                    const float* __restrict__ C,
                                                    const float* __restrict__ gamma,
                                                    const float* __restrict__ beta,
                                                    float* __restrict__ out) {
  const int row = blockIdx.x;
  const int b = row >> 10;
  const int tid = threadIdx.x;
  __shared__ float qs[DD];
  __shared__ float ps[LK];
  __shared__ float ys[DD];
  __shared__ float red[256];
  const float* qp = Q + (size_t)row * DD;
  const float* cb = C + (size_t)b * LK * DD;
  for (int d = tid; d < DD; d += 256) qs[d] = qp[d];
  __syncthreads();
  for (int k = tid; k < LK; k += 256) {
    const float* cr = cb + (size_t)k * DD;
    float s = 0.f;
    for (int d = 0; d < DD; ++d) s += qs[d] * cr[d];
    s *= 0.044194173824159216f;
    float e2 = __expf(2.f * s);
    float th = (e2 - 1.f) / (e2 + 1.f);
    ps[k] = __expf(th);
  }
  __syncthreads();
  float dsum = 0.f;
  for (int k = tid; k < LK; k += 256) dsum += ps[k];
  red[tid] = dsum;
  __syncthreads();
  for (int off = 128; off; off >>= 1) {
    if (tid < off) red[tid] += red[tid + off];
    __syncthreads();
  }
  float inv = 1.f / red[0];
  __syncthreads();
  for (int d = tid; d < DD; d += 256) {
    float o = 0.f;
    for (int k = 0; k < LK; ++k) o += ps[k] * cb[(size_t)k * DD + d];
    ys[d] = o * inv + qs[d];
  }
  __syncthreads();
  float s1 = 0.f;
  for (int d = tid; d < DD; d += 256) s1 += ys[d];
  red[tid] = s1;
  __syncthreads();
  for (int off = 128; off; off >>= 1) {
    if (tid < off) red[tid] += red[tid + off];
    __syncthreads();
  }
  float mean = red[0] * (1.f / DD);
  __syncthreads();
  float s2 = 0.f;
  for (int d = tid; d < DD; d += 256) {
    float v = ys[d] - mean;
    s2 += v * v;
  }
  red[tid] = s2;
  __syncthreads();
  for (int off = 128; off; off >>= 1) {
    if (tid < off) red[tid] += red[tid + off];
    __syncthreads();
  }
  float rstd = rsqrtf(red[0] * (1.f / DD) + 1e-6f);
  for (int d = tid; d < DD; d += 256)
    out[(size_t)row * DD + d] = gamma[d] * ((ys[d] - mean) * rstd) + beta[d];
}

extern "C" void kernel_launch(void* const* d_in, const int* in_sizes, int n_in,
                              void* d_out, int out_size, void* d_ws, size_t ws_size,
                              hipStream_t stream) {
  const float* Qf = (const float*)d_in[0];
  const float* Cf = (const float*)d_in[1];
  const float* gamma = (const float*)d_in[2];
  const float* beta = (const float*)d_in[3];
  float* out = (float*)d_out;
  const size_t nelem = (size_t)NB * LK * DD;  // 8,388,608
  const size_t need = nelem * 2 * 2;          // Cb + Ctb (33.5 MB)
  if (ws_size >= need) {
    uint16_t* Cb = (uint16_t*)d_ws;
    uint16_t* Ctb = Cb + nelem;
    prep_kernel<<<dim3(LK / 32, DD / 32, NB), dim3(32, 8), 0, stream>>>(Cf, Cb, Ctb);
    attn_kernel<<<256, 512, 0, stream>>>(Cb, Ctb, Qf, gamma, beta, out);
  } else {
    naive_kernel<<<NB * LQ, 256, 0, stream>>>(Qf, Cf, gamma, beta, out);
  }
}

// Round 12
// 97.271 us; speedup vs baseline: 2.5071x; 2.5071x over previous
//
#include <hip/hip_runtime.h>
#include <hip/hip_bf16.h>
#include <cstdint>

#define LQ 1024
#define LK 1024
#define DD 512
#define NB 16
#define QB 64
#define KB 32
#define NT (LK / KB)
#define CSTRIDE 1088  // 1024 + 64: linear-in-s S^T reads with 8-quad bank spread
#define CSZ (32 * CSTRIDE)

typedef short bf16x8 __attribute__((ext_vector_type(8)));
typedef float f32x4 __attribute__((ext_vector_type(4)));

__device__ __forceinline__ uint16_t f2bf(float f) {
  uint32_t u = __builtin_bit_cast(uint32_t, f);
  u = (u + 0x7fffu + ((u >> 16) & 1u)) >> 16;  // RNE; inputs finite
  return (uint16_t)u;
}

__device__ __forceinline__ void load_lds16(const void* g, void* l) {
  __builtin_amdgcn_global_load_lds(
      (const __attribute__((address_space(1))) uint32_t*)g,
      (__attribute__((address_space(3))) uint32_t*)l, 16, 0, 0);
}

// ---------- fused prepass: C fp32 -> Cb bf16 [B][Lk][D] + Ct bf16 [B][D][Lk] ----------
__global__ __launch_bounds__(256) void prep_kernel(const float* __restrict__ c,
                                                   uint16_t* __restrict__ cb,
                                                   uint16_t* __restrict__ ct) {
  __shared__ float t[32][33];
  const int k0 = blockIdx.x * 32, d0 = blockIdx.y * 32, b = blockIdx.z;
  const float* src = c + (size_t)b * LK * DD;
  uint16_t* cbd = cb + (size_t)b * LK * DD;
  uint16_t* ctd = ct + (size_t)b * DD * LK;
  const int tx = threadIdx.x, ty = threadIdx.y;
  for (int j = 0; j < 4; ++j) {
    int k = ty + j * 8;
    float v = src[(size_t)(k0 + k) * DD + d0 + tx];
    t[k][tx] = v;
    cbd[(size_t)(k0 + k) * DD + d0 + tx] = f2bf(v);
  }
  __syncthreads();
  for (int j = 0; j < 4; ++j) {
    int d = ty + j * 8;
    ctd[(size_t)(d0 + d) * LK + k0 + tx] = f2bf(t[tx][d]);
  }
}

// ---------------- fused attention + residual + LayerNorm ----------------
// grid = 256 (B=16 x 16 q-blocks of 64 rows), block = 512 (8 waves).
// Single-buffered LDS tiles (74 KB/block) -> HW can co-schedule 2 blocks/CU
// (148 KB LDS, ~108 VGPR <= 128). launch_bounds(512,2) — NOT (512,4): the
// ",4" hint caps VGPR at 64 and spills (r11: 246 us, WRITE 103 MB).
// 3 barriers/iter; staging DMAs overlap PV within-block; co-resident block
// fills the remaining stalls (m97-style implicit cross-block overlap).
__global__ __launch_bounds__(512, 2) void attn_kernel(
    const uint16_t* __restrict__ Cb, const uint16_t* __restrict__ Ctb,
    const float* __restrict__ Qf, const float* __restrict__ gamma,
    const float* __restrict__ beta, float* __restrict__ out) {
  __shared__ uint4 cs4[CSZ / 16];         // 34 KB C tile [32 kk][512 d] bf16
  __shared__ uint4 cts4[32 * 1024 / 16];  // 32 KB Ct tile [512 d][32 kk] bf16
  __shared__ char plds[64 * 80];          // 5 KB P [64 q][32 kk], stride 80
  __shared__ float denom_s[QB];
  __shared__ float rsum_s[QB], rsumsq_s[QB], mean_s[QB], rstd_s[QB];

  const int tid = threadIdx.x;
  const int w = tid >> 6, l = tid & 63, c = l & 15, g = l >> 4;
  const int orig = blockIdx.x;
  const int virt = ((orig & 7) << 5) | (orig >> 3);  // 256 % 8 == 0: bijective
  const int b = virt >> 4, qblk = virt & 15;
  const int q0 = qblk * QB;
  const int mt = w & 1, qt = w >> 1;
  const float scale = 0.044194173824159216f;  // 1/sqrt(512)

  if (tid < QB) { denom_s[tid] = 0.f; rsum_s[tid] = 0.f; rsumsq_s[tid] = 0.f; }

  // Q fragments (B operand of S^T) from fp32, converted in-register
  bf16x8 qfrag[16];
  {
    const float* qrow = Qf + ((size_t)b * LQ + q0 + qt * 16 + c) * DD;
    for (int s = 0; s < 16; ++s) {
      float4 a0 = *(const float4*)(qrow + s * 32 + g * 8);
      float4 a1 = *(const float4*)(qrow + s * 32 + g * 8 + 4);
      ushort4 u0, u1;
      u0.x = f2bf(a0.x); u0.y = f2bf(a0.y); u0.z = f2bf(a0.z); u0.w = f2bf(a0.w);
      u1.x = f2bf(a1.x); u1.y = f2bf(a1.y); u1.z = f2bf(a1.z); u1.w = f2bf(a1.w);
      union { ushort4 u[2]; bf16x8 v; } pk;
      pk.u[0] = u0; pk.u[1] = u1;
      qfrag[s] = pk.v;
    }
  }

  const int kkA = mt * 16 + c;
  const int aoff = kkA * CSTRIDE + ((g ^ (kkA & 3)) * 16);

  f32x4 oacc[4][4];
  for (int i = 0; i < 4; ++i)
    for (int j = 0; j < 4; ++j) oacc[i][j] = (f32x4){0.f, 0.f, 0.f, 0.f};
  float dacc = 0.f;

  const char* cbyte = (const char*)Cb + (size_t)b * LK * DD * 2;
  const char* ctbyte = (const char*)Ctb + (size_t)b * DD * LK * 2;

  int csrcoff[4];
  for (int j = 0; j < 4; ++j) {
    int r = w * 4 + j;
    csrcoff[j] = r * 1024 + ((l * 16) ^ ((r & 3) << 4));
  }

  char* cs = (char*)cs4;
  char* cts = (char*)cts4;
  const int pwoff = (qt * 16 + c) * 80 + (mt * 16 + g * 4) * 2;
  const int proff = c * 80 + g * 16;

  auto stageC = [&](int kt2) {
    const char* s0 = cbyte + (size_t)kt2 * 32768;
    for (int j = 0; j < 4; ++j)
      load_lds16(s0 + csrcoff[j], cs + (w * 4 + j) * CSTRIDE);
  };
  auto stageCT = [&](int kt2) {
    const int kk0 = kt2 * KB;
    for (int j = 0; j < 4; ++j) {
      int d0l = w * 64 + j * 16;
      int d = d0l + (l >> 2);
      const char* src =
          ctbyte + (size_t)d * 2048 + kk0 * 2 + (((l & 3) * 16) ^ ((d & 3) << 4));
      load_lds16(src, cts + d0l * 64);
    }
  };

  stageC(0);
  stageCT(0);
  __syncthreads();  // prologue drain; zero-inits visible

  for (int kt = 0; kt < NT; ++kt) {
    // S^T(kt): lane (c,g) -> kk=mt*16+g*4+i, q=qt*16+c; 4 independent chains
    f32x4 s0v = {0.f, 0.f, 0.f, 0.f}, s1v = {0.f, 0.f, 0.f, 0.f};
    f32x4 s2v = {0.f, 0.f, 0.f, 0.f}, s3v = {0.f, 0.f, 0.f, 0.f};
    {
      const char* ar = cs + aoff;
      for (int s = 0; s < 4; ++s) {
        bf16x8 a0 = *(const bf16x8*)(ar + s * 64);
        bf16x8 a1 = *(const bf16x8*)(ar + (s + 4) * 64);
        bf16x8 a2 = *(const bf16x8*)(ar + (s + 8) * 64);
        bf16x8 a3 = *(const bf16x8*)(ar + (s + 12) * 64);
        s0v = __builtin_amdgcn_mfma_f32_16x16x32_bf16(a0, qfrag[s], s0v, 0, 0, 0);
        s1v = __builtin_amdgcn_mfma_f32_16x16x32_bf16(a1, qfrag[s + 4], s1v, 0, 0, 0);
        s2v = __builtin_amdgcn_mfma_f32_16x16x32_bf16(a2, qfrag[s + 8], s2v, 0, 0, 0);
        s3v = __builtin_amdgcn_mfma_f32_16x16x32_bf16(a3, qfrag[s + 12], s3v, 0, 0, 0);
      }
    }
    // P(kt) = exp(tanh(s*scale)) in [e^-1, e^1] -> no max tracking
    {
      float pv[4];
      for (int i = 0; i < 4; ++i) {
        float sv = ((s0v[i] + s1v[i]) + (s2v[i] + s3v[i])) * scale;
        float e2 = __expf(sv * 2.f);
        float r = __builtin_amdgcn_rcpf(e2 + 1.f);
        float th = (e2 - 1.f) * r;
        float p = __expf(th);
        pv[i] = p;
        dacc += p;
      }
      uint2 pk;
      asm("v_cvt_pk_bf16_f32 %0, %1, %2" : "=v"(pk.x) : "v"(pv[0]), "v"(pv[1]));
      asm("v_cvt_pk_bf16_f32 %0, %1, %2" : "=v"(pk.y) : "v"(pv[2]), "v"(pv[3]));
      *(uint2*)(plds + pwoff) = pk;
    }
    // bar1: all cs reads + P write done (DS only) -> cs is free to restage
    asm volatile("s_waitcnt lgkmcnt(0)" ::: "memory");
    __builtin_amdgcn_s_barrier();
    __builtin_amdgcn_sched_barrier(0);
    if (kt + 1 < NT) stageC(kt + 1);  // DMA into cs, overlaps PV below

    // PV(kt): O[q][d] += P[q][kk] * C[kk][d]; wave w owns d in [w*64, w*64+64)
    {
      bf16x8 pa[4], pb[4];
      for (int q2 = 0; q2 < 4; ++q2)
        pa[q2] = *(const bf16x8*)(plds + proff + q2 * 1280);
      for (int nt = 0; nt < 4; ++nt) {
        int d = w * 64 + nt * 16 + c;
        pb[nt] = *(const bf16x8*)(cts + d * 64 + ((g * 16) ^ ((d & 3) << 4)));
      }
      for (int q2 = 0; q2 < 4; ++q2)
        for (int n2 = 0; n2 < 4; ++n2)
          oacc[q2][n2] =
              __builtin_amdgcn_mfma_f32_16x16x32_bf16(pa[q2], pb[n2], oacc[q2][n2], 0, 0, 0);
    }
    // bar2: all cts + plds reads done -> cts free to restage
    asm volatile("s_waitcnt lgkmcnt(0)" ::: "memory");
    __builtin_amdgcn_s_barrier();
    __builtin_amdgcn_sched_barrier(0);
    if (kt + 1 < NT) stageCT(kt + 1);  // DMA into cts
    // bar3: full drain -- both DMAs landed before next iter's reads
    __syncthreads();
  }

  // denom: reduce over g (shfl 16,32), combine mt-halves via LDS atomics
  float dv = dacc;
  dv += __shfl_xor(dv, 16);
  dv += __shfl_xor(dv, 32);
  if (l < 16) atomicAdd(&denom_s[qt * 16 + l], dv);
  __syncthreads();

  // epilogue: y = O/denom + query (fp32), then LayerNorm over D
  const float* qsrc = Qf + ((size_t)b * LQ + q0) * DD;
  for (int q2 = 0; q2 < 4; ++q2)
    for (int i = 0; i < 4; ++i) {
      int row = q2 * 16 + g * 4 + i;
      float inv = 1.f / denom_s[row];
      for (int nt = 0; nt < 4; ++nt) {
        int d = w * 64 + nt * 16 + c;
        float o = oacc[q2][nt][i] * inv + qsrc[(size_t)row * DD + d];
        oacc[q2][nt][i] = o;
      }
    }
  for (int q2 = 0; q2 < 4; ++q2)
    for (int i = 0; i < 4; ++i) {
      float s1 = 0.f, s2 = 0.f;
      for (int nt = 0; nt < 4; ++nt) {
        float v = oacc[q2][nt][i];
        s1 += v;
        s2 += v * v;
      }
      s1 += __shfl_xor(s1, 1); s2 += __shfl_xor(s2, 1);
      s1 += __shfl_xor(s1, 2); s2 += __shfl_xor(s2, 2);
      s1 += __shfl_xor(s1, 4); s2 += __shfl_xor(s2, 4);
      s1 += __shfl_xor(s1, 8); s2 += __shfl_xor(s2, 8);
      if (c == 0) {
        int row = q2 * 16 + g * 4 + i;
        atomicAdd(&rsum_s[row], s1);
        atomicAdd(&rsumsq_s[row], s2);
      }
    }
  __syncthreads();
  if (tid < QB) {
    float m = rsum_s[tid] * (1.f / DD);
    float var = rsumsq_s[tid] * (1.f / DD) - m * m;
    mean_s[tid] = m;
    rstd_s[tid] = rsqrtf(fmaxf(var, 0.f) + 1e-6f);
  }
  __syncthreads();
  float* op = out + ((size_t)b * LQ + q0) * DD;
  for (int q2 = 0; q2 < 4; ++q2)
    for (int i = 0; i < 4; ++i) {
      int row = q2 * 16 + g * 4 + i;
      float m = mean_s[row], r = rstd_s[row];
      for (int nt = 0; nt < 4; ++nt) {
        int d = w * 64 + nt * 16 + c;
        op[(size_t)row * DD + d] = gamma[d] * ((oacc[q2][nt][i] - m) * r) + beta[d];
      }
    }
}

// ---------------- slow-but-correct fallback (if ws too small) ----------------
__global__ __launch_bounds__(256) void naive_kernel(const float* __restrict__ Q,
                                                    const float* __restrict__ C,
                                                    const float* __restrict__ gamma,
                                                    const float* __restrict__ beta,
                                                    float* __restrict__ out) {
  const int row = blockIdx.x;
  const int b = row >> 10;
  const int tid = threadIdx.x;
  __shared__ float qs[DD];
  __shared__ float ps[LK];
  __shared__ float ys[DD];
  __shared__ float red[256];
  const float* qp = Q + (size_t)row * DD;
  const float* cb = C + (size_t)b * LK * DD;
  for (int d = tid; d < DD; d += 256) qs[d] = qp[d];
  __syncthreads();
  for (int k = tid; k < LK; k += 256) {
    const float* cr = cb + (size_t)k * DD;
    float s = 0.f;
    for (int d = 0; d < DD; ++d) s += qs[d] * cr[d];
    s *= 0.044194173824159216f;
    float e2 = __expf(2.f * s);
    float th = (e2 - 1.f) / (e2 + 1.f);
    ps[k] = __expf(th);
  }
  __syncthreads();
  float dsum = 0.f;
  for (int k = tid; k < LK; k += 256) dsum += ps[k];
  red[tid] = dsum;
  __syncthreads();
  for (int off = 128; off; off >>= 1) {
    if (tid < off) red[tid] += red[tid + off];
    __syncthreads();
  }
  float inv = 1.f / red[0];
  __syncthreads();
  for (int d = tid; d < DD; d += 256) {
    float o = 0.f;
    for (int k = 0; k < LK; ++k) o += ps[k] * cb[(size_t)k * DD + d];
    ys[d] = o * inv + qs[d];
  }
  __syncthreads();
  float s1 = 0.f;
  for (int d = tid; d < DD; d += 256) s1 += ys[d];
  red[tid] = s1;
  __syncthreads();
  for (int off = 128; off; off >>= 1) {
    if (tid < off) red[tid] += red[tid + off];
    __syncthreads();
  }
  float mean = red[0] * (1.f / DD);
  __syncthreads();
  float s2 = 0.f;
  for (int d = tid; d < DD; d += 256) {
    float v = ys[d] - mean;
    s2 += v * v;
  }
  red[tid] = s2;
  __syncthreads();
  for (int off = 128; off; off >>= 1) {
    if (tid < off) red[tid] += red[tid + off];
    __syncthreads();
  }
  float rstd = rsqrtf(red[0] * (1.f / DD) + 1e-6f);
  for (int d = tid; d < DD; d += 256)
    out[(size_t)row * DD + d] = gamma[d] * ((ys[d] - mean) * rstd) + beta[d];
}

extern "C" void kernel_launch(void* const* d_in, const int* in_sizes, int n_in,
                              void* d_out, int out_size, void* d_ws, size_t ws_size,
                              hipStream_t stream) {
  const float* Qf = (const float*)d_in[0];
  const float* Cf = (const float*)d_in[1];
  const float* gamma = (const float*)d_in[2];
  const float* beta = (const float*)d_in[3];
  float* out = (float*)d_out;
  const size_t nelem = (size_t)NB * LK * DD;  // 8,388,608
  const size_t need = nelem * 2 * 2;          // Cb + Ctb (33.5 MB)
  if (ws_size >= need) {
    uint16_t* Cb = (uint16_t*)d_ws;
    uint16_t* Ctb = Cb + nelem;
    prep_kernel<<<dim3(LK / 32, DD / 32, NB), dim3(32, 8), 0, stream>>>(Cf, Cb, Ctb);
    attn_kernel<<<256, 512, 0, stream>>>(Cb, Ctb, Qf, gamma, beta, out);
  } else {
    naive_kernel<<<NB * LQ, 256, 0, stream>>>(Qf, Cf, gamma, beta, out);
  }
}

// Round 13
// 82.321 us; speedup vs baseline: 2.9624x; 1.1816x over previous
//
#include <hip/hip_runtime.h>
#include <hip/hip_bf16.h>
#include <cstdint>

#define LQ 1024
#define LK 1024
#define DD 512
#define NB 16
#define QB 64
#define KB 32
#define NT (LK / KB)
#define CSTRIDE 1088  // 1024 + 64: linear-in-s S^T reads with 8-quad bank spread
#define CSZ (32 * CSTRIDE)

typedef short bf16x8 __attribute__((ext_vector_type(8)));
typedef float f32x4 __attribute__((ext_vector_type(4)));

__device__ __forceinline__ uint16_t f2bf(float f) {
  uint32_t u = __builtin_bit_cast(uint32_t, f);
  u = (u + 0x7fffu + ((u >> 16) & 1u)) >> 16;  // RNE; inputs finite
  return (uint16_t)u;
}

__device__ __forceinline__ void load_lds16(const void* g, void* l) {
  __builtin_amdgcn_global_load_lds(
      (const __attribute__((address_space(1))) uint32_t*)g,
      (__attribute__((address_space(3))) uint32_t*)l, 16, 0, 0);
}

// ---------- fused prepass: C fp32 -> Cb bf16 [B][Lk][D] + Ct bf16 [B][D][Lk] ----------
__global__ __launch_bounds__(256) void prep_kernel(const float* __restrict__ c,
                                                   uint16_t* __restrict__ cb,
                                                   uint16_t* __restrict__ ct) {
  __shared__ float t[32][33];
  const int k0 = blockIdx.x * 32, d0 = blockIdx.y * 32, b = blockIdx.z;
  const float* src = c + (size_t)b * LK * DD;
  uint16_t* cbd = cb + (size_t)b * LK * DD;
  uint16_t* ctd = ct + (size_t)b * DD * LK;
  const int tx = threadIdx.x, ty = threadIdx.y;
  for (int j = 0; j < 4; ++j) {
    int k = ty + j * 8;
    float v = src[(size_t)(k0 + k) * DD + d0 + tx];
    t[k][tx] = v;
    cbd[(size_t)(k0 + k) * DD + d0 + tx] = f2bf(v);
  }
  __syncthreads();
  for (int j = 0; j < 4; ++j) {
    int d = ty + j * 8;
    ctd[(size_t)(d0 + d) * LK + k0 + tx] = f2bf(t[tx][d]);
  }
}

// ---------------- fused attention + residual + LayerNorm ----------------
// grid = 256 (B=16 x 16 q-blocks of 64 rows), block = 512 (8 waves).
// Round-9 structure (best measured: 76.4 us attn / 83.2 total) + ONE delta:
// v_cvt_pk_bf16_f32 for the P pack (r10: VALUBusy 27->24.4%, mechanism clean;
// r10's regression tracked pb-hoist VGPR + lockstep setprio, both excluded).
// Rhythm: stage(kt+1) async -> S^T(kt) -> P(kt) -> lgkm+s_barrier -> PV(kt)
//         -> __syncthreads (full drain; staging had the whole iter in flight)
__global__ __launch_bounds__(512, 2) void attn_kernel(
    const uint16_t* __restrict__ Cb, const uint16_t* __restrict__ Ctb,
    const float* __restrict__ Qf, const float* __restrict__ gamma,
    const float* __restrict__ beta, float* __restrict__ out) {
  __shared__ uint4 cs4[2 * CSZ / 16];         // 2 x 34 KB C tile [32 kk][512 d]
  __shared__ uint4 cts4[2 * 32 * 1024 / 16];  // 2 x 32 KB Ct tile [512 d][32 kk]
  __shared__ char plds[64 * 80];              // 5 KB P [64 q][32 kk], stride 80
  __shared__ float denom_s[QB];
  __shared__ float rsum_s[QB], rsumsq_s[QB], mean_s[QB], rstd_s[QB];

  const int tid = threadIdx.x;
  const int w = tid >> 6, l = tid & 63, c = l & 15, g = l >> 4;
  const int orig = blockIdx.x;
  const int virt = ((orig & 7) << 5) | (orig >> 3);  // 256 % 8 == 0: bijective
  const int b = virt >> 4, qblk = virt & 15;
  const int q0 = qblk * QB;
  const int mt = w & 1, qt = w >> 1;
  const float scale = 0.044194173824159216f;  // 1/sqrt(512)

  if (tid < QB) { denom_s[tid] = 0.f; rsum_s[tid] = 0.f; rsumsq_s[tid] = 0.f; }

  // Q fragments (B operand of S^T) from fp32, converted in-register
  bf16x8 qfrag[16];
  {
    const float* qrow = Qf + ((size_t)b * LQ + q0 + qt * 16 + c) * DD;
    for (int s = 0; s < 16; ++s) {
      float4 a0 = *(const float4*)(qrow + s * 32 + g * 8);
      float4 a1 = *(const float4*)(qrow + s * 32 + g * 8 + 4);
      ushort4 u0, u1;
      u0.x = f2bf(a0.x); u0.y = f2bf(a0.y); u0.z = f2bf(a0.z); u0.w = f2bf(a0.w);
      u1.x = f2bf(a1.x); u1.y = f2bf(a1.y); u1.z = f2bf(a1.z); u1.w = f2bf(a1.w);
      union { ushort4 u[2]; bf16x8 v; } pk;
      pk.u[0] = u0; pk.u[1] = u1;
      qfrag[s] = pk.v;
    }
  }

  const int kkA = mt * 16 + c;
  const int aoff = kkA * CSTRIDE + ((g ^ (kkA & 3)) * 16);

  f32x4 oacc[4][4];
  for (int i = 0; i < 4; ++i)
    for (int j = 0; j < 4; ++j) oacc[i][j] = (f32x4){0.f, 0.f, 0.f, 0.f};
  float dacc = 0.f;

  const char* cbyte = (const char*)Cb + (size_t)b * LK * DD * 2;
  const char* ctbyte = (const char*)Ctb + (size_t)b * DD * LK * 2;

  // staging source offsets (source pre-swizzled; LDS dest linear per DMA rule)
  int csrcoff[4];
  for (int j = 0; j < 4; ++j) {
    int r = w * 4 + j;
    csrcoff[j] = r * 1024 + ((l * 16) ^ ((r & 3) << 4));
  }

  char* cs0 = (char*)cs4;
  char* cs1 = cs0 + CSZ;
  char* cts0 = (char*)cts4;
  char* cts1 = cts0 + 32 * 1024;
  const int pwoff = (qt * 16 + c) * 80 + (mt * 16 + g * 4) * 2;
  const int proff = c * 80 + g * 16;

  auto stageC = [&](char* dst, int kt2) {
    const char* s0 = cbyte + (size_t)kt2 * 32768;
    for (int j = 0; j < 4; ++j)
      load_lds16(s0 + csrcoff[j], dst + (w * 4 + j) * CSTRIDE);
  };
  auto stageCT = [&](char* dst, int kt2) {
    const int kk0 = kt2 * KB;
    for (int j = 0; j < 4; ++j) {  // wave w -> d rows w*64 .. w*64+63, 16/issue
      int d0l = w * 64 + j * 16;
      int d = d0l + (l >> 2);
      const char* src =
          ctbyte + (size_t)d * 2048 + kk0 * 2 + (((l & 3) * 16) ^ ((d & 3) << 4));
      load_lds16(src, dst + d0l * 64);
    }
  };

  stageC(cs0, 0);
  stageCT(cts0, 0);
  __syncthreads();  // prologue drain; zero-inits visible

  for (int kt = 0; kt < NT; ++kt) {
    const int cur = kt & 1;
    const char* csR = cur ? cs1 : cs0;
    const char* ctsR = cur ? cts1 : cts0;
    if (kt + 1 < NT) {  // async staging, in flight across the mid barrier
      stageC(cur ? cs0 : cs1, kt + 1);
      stageCT(cur ? cts0 : cts1, kt + 1);
    }
    // S^T(kt): lane (c,g) -> kk=mt*16+g*4+i, q=qt*16+c; 4 independent chains
    f32x4 s0v = {0.f, 0.f, 0.f, 0.f}, s1v = {0.f, 0.f, 0.f, 0.f};
    f32x4 s2v = {0.f, 0.f, 0.f, 0.f}, s3v = {0.f, 0.f, 0.f, 0.f};
    {
      const char* ar = csR + aoff;
      for (int s = 0; s < 4; ++s) {
        bf16x8 a0 = *(const bf16x8*)(ar + s * 64);
        bf16x8 a1 = *(const bf16x8*)(ar + (s + 4) * 64);
        bf16x8 a2 = *(const bf16x8*)(ar + (s + 8) * 64);
        bf16x8 a3 = *(const bf16x8*)(ar + (s + 12) * 64);
        s0v = __builtin_amdgcn_mfma_f32_16x16x32_bf16(a0, qfrag[s], s0v, 0, 0, 0);
        s1v = __builtin_amdgcn_mfma_f32_16x16x32_bf16(a1, qfrag[s + 4], s1v, 0, 0, 0);
        s2v = __builtin_amdgcn_mfma_f32_16x16x32_bf16(a2, qfrag[s + 8], s2v, 0, 0, 0);
        s3v = __builtin_amdgcn_mfma_f32_16x16x32_bf16(a3, qfrag[s + 12], s3v, 0, 0, 0);
      }
    }
    // P(kt) = exp(tanh(s*scale)) in [e^-1, e^1] -> no max tracking
    {
      float pv[4];
      for (int i = 0; i < 4; ++i) {
        float sv = ((s0v[i] + s1v[i]) + (s2v[i] + s3v[i])) * scale;
        float e2 = __expf(sv * 2.f);
        float r = __builtin_amdgcn_rcpf(e2 + 1.f);
        float th = (e2 - 1.f) * r;
        float p = __expf(th);
        pv[i] = p;
        dacc += p;
      }
      uint2 pk;
      asm("v_cvt_pk_bf16_f32 %0, %1, %2" : "=v"(pk.x) : "v"(pv[0]), "v"(pv[1]));
      asm("v_cvt_pk_bf16_f32 %0, %1, %2" : "=v"(pk.y) : "v"(pv[2]), "v"(pv[3]));
      *(uint2*)(plds + pwoff) = pk;
    }
    // mid barrier: P + this tile's reads done (DS only); staging stays in flight
    asm volatile("s_waitcnt lgkmcnt(0)" ::: "memory");
    __builtin_amdgcn_s_barrier();
    __builtin_amdgcn_sched_barrier(0);

    // PV(kt): O[q][d] += P[q][kk] * C[kk][d]; wave w owns d in [w*64, w*64+64)
    {
      bf16x8 pa[4], pb[4];
      for (int q2 = 0; q2 < 4; ++q2)
        pa[q2] = *(const bf16x8*)(plds + proff + q2 * 1280);
      for (int nt = 0; nt < 4; ++nt) {
        int d = w * 64 + nt * 16 + c;
        pb[nt] = *(const bf16x8*)(ctsR + d * 64 + ((g * 16) ^ ((d & 3) << 4)));
      }
      for (int q2 = 0; q2 < 4; ++q2)
        for (int n2 = 0; n2 < 4; ++n2)
          oacc[q2][n2] =
              __builtin_amdgcn_mfma_f32_16x16x32_bf16(pa[q2], pb[n2], oacc[q2][n2], 0, 0, 0);
    }
    __syncthreads();  // end barrier: next tile staged (full drain) + P reads done
  }

  // denom: reduce over g (shfl 16,32), combine mt-halves via LDS atomics
  float dv = dacc;
  dv += __shfl_xor(dv, 16);
  dv += __shfl_xor(dv, 32);
  if (l < 16) atomicAdd(&denom_s[qt * 16 + l], dv);
  __syncthreads();

  // epilogue: y = O/denom + query (fp32), then LayerNorm over D
  const float* qsrc = Qf + ((size_t)b * LQ + q0) * DD;
  for (int q2 = 0; q2 < 4; ++q2)
    for (int i = 0; i < 4; ++i) {
      int row = q2 * 16 + g * 4 + i;
      float inv = 1.f / denom_s[row];
      for (int nt = 0; nt < 4; ++nt) {
        int d = w * 64 + nt * 16 + c;
        float o = oacc[q2][nt][i] * inv + qsrc[(size_t)row * DD + d];
        oacc[q2][nt][i] = o;
      }
    }
  for (int q2 = 0; q2 < 4; ++q2)
    for (int i = 0; i < 4; ++i) {
      float s1 = 0.f, s2 = 0.f;
      for (int nt = 0; nt < 4; ++nt) {
        float v = oacc[q2][nt][i];
        s1 += v;
        s2 += v * v;
      }
      s1 += __shfl_xor(s1, 1); s2 += __shfl_xor(s2, 1);
      s1 += __shfl_xor(s1, 2); s2 += __shfl_xor(s2, 2);
      s1 += __shfl_xor(s1, 4); s2 += __shfl_xor(s2, 4);
      s1 += __shfl_xor(s1, 8); s2 += __shfl_xor(s2, 8);
      if (c == 0) {
        int row = q2 * 16 + g * 4 + i;
        atomicAdd(&rsum_s[row], s1);
        atomicAdd(&rsumsq_s[row], s2);
      }
    }
  __syncthreads();
  if (tid < QB) {
    float m = rsum_s[tid] * (1.f / DD);
    float var = rsumsq_s[tid] * (1.f / DD) - m * m;
    mean_s[tid] = m;
    rstd_s[tid] = rsqrtf(fmaxf(var, 0.f) + 1e-6f);
  }
  __syncthreads();
  float* op = out + ((size_t)b * LQ + q0) * DD;
  for (int q2 = 0; q2 < 4; ++q2)
    for (int i = 0; i < 4; ++i) {
      int row = q2 * 16 + g * 4 + i;
      float m = mean_s[row], r = rstd_s[row];
      for (int nt = 0; nt < 4; ++nt) {
        int d = w * 64 + nt * 16 + c;
        op[(size_t)row * DD + d] = gamma[d] * ((oacc[q2][nt][i] - m) * r) + beta[d];
      }
    }
}

// ---------------- slow-but-correct fallback (if ws too small) ----------------
__global__ __launch_bounds__(256) void naive_kernel(const float* __restrict__ Q,
                                                    const float* __restrict__ C,
                                                    const float* __restrict__ gamma,
                                                    const float* __restrict__ beta,
                                                    float* __restrict__ out) {
  const int row = blockIdx.x;
  const int b = row >> 10;
  const int tid = threadIdx.x;
  __shared__ float qs[DD];
  __shared__ float ps[LK];
  __shared__ float ys[DD];
  __shared__ float red[256];
  const float* qp = Q + (size_t)row * DD;
  const float* cb = C + (size_t)b * LK * DD;
  for (int d = tid; d < DD; d += 256) qs[d] = qp[d];
  __syncthreads();
  for (int k = tid; k < LK; k += 256) {
    const float* cr = cb + (size_t)k * DD;
    float s = 0.f;
    for (int d = 0; d < DD; ++d) s += qs[d] * cr[d];
    s *= 0.044194173824159216f;
    float e2 = __expf(2.f * s);
    float th = (e2 - 1.f) / (e2 + 1.f);
    ps[k] = __expf(th);
  }
  __syncthreads();
  float dsum = 0.f;
  for (int k = tid; k < LK; k += 256) dsum += ps[k];
  red[tid] = dsum;
  __syncthreads();
  for (int off = 128; off; off >>= 1) {
    if (tid < off) red[tid] += red[tid + off];
    __syncthreads();
  }
  float inv = 1.f / red[0];
  __syncthreads();
  for (int d = tid; d < DD; d += 256) {
    float o = 0.f;
    for (int k = 0; k < LK; ++k) o += ps[k] * cb[(size_t)k * DD + d];
    ys[d] = o * inv + qs[d];
  }
  __syncthreads();
  float s1 = 0.f;
  for (int d = tid; d < DD; d += 256) s1 += ys[d];
  red[tid] = s1;
  __syncthreads();
  for (int off = 128; off; off >>= 1) {
    if (tid < off) red[tid] += red[tid + off];
    __syncthreads();
  }
  float mean = red[0] * (1.f / DD);
  __syncthreads();
  float s2 = 0.f;
  for (int d = tid; d < DD; d += 256) {
    float v = ys[d] - mean;
    s2 += v * v;
  }
  red[tid] = s2;
  __syncthreads();
  for (int off = 128; off; off >>= 1) {
    if (tid < off) red[tid] += red[tid + off];
    __syncthreads();
  }
  float rstd = rsqrtf(red[0] * (1.f / DD) + 1e-6f);
  for (int d = tid; d < DD; d += 256)
    out[(size_t)row * DD + d] = gamma[d] * ((ys[d] - mean) * rstd) + beta[d];
}

extern "C" void kernel_launch(void* const* d_in, const int* in_sizes, int n_in,
                              void* d_out, int out_size, void* d_ws, size_t ws_size,
                              hipStream_t stream) {
  const float* Qf = (const float*)d_in[0];
  const float* Cf = (const float*)d_in[1];
  const float* gamma = (const float*)d_in[2];
  const float* beta = (const float*)d_in[3];
  float* out = (float*)d_out;
  const size_t nelem = (size_t)NB * LK * DD;  // 8,388,608
  const size_t need = nelem * 2 * 2;          // Cb + Ctb (33.5 MB)
  if (ws_size >= need) {
    uint16_t* Cb = (uint16_t*)d_ws;
    uint16_t* Ctb = Cb + nelem;
    prep_kernel<<<dim3(LK / 32, DD / 32, NB), dim3(32, 8), 0, stream>>>(Cf, Cb, Ctb);
    attn_kernel<<<256, 512, 0, stream>>>(Cb, Ctb, Qf, gamma, beta, out);
  } else {
    naive_kernel<<<NB * LQ, 256, 0, stream>>>(Qf, Cf, gamma, beta, out);
  }
}